// Round 8
// baseline (509.861 us; speedup 1.0000x reference)
//
#include <hip/hip_runtime.h>

// DEMA over x:(B=32, T=4096, F=512) fp32, scan along T.
// Chunked-with-halo parallelization: A = [[1-a,1-a],[-a*b,1-a*b]] has
// |lambda| = sqrt(0.7) ~ 0.8367 -> ||A^96|| ~ 3.6e-8, so a 96-step warmup
// from the cheap init (s=x[t-1], b=x[t]-x[t-1]) reproduces the state to
// ~1e-7 (invisible vs the ~0.03 fp32-reassociation absmax). Chunks of T
// are independent given the halo -> fully parallel.
//
// Rounds 4-5 measured: BW pinned at ~2.5 TB/s with 1024 waves and ~1 KB in
// flight/wave (Little's law closes at ~950 cyc latency). The compiler sinks
// prefetch loads regardless of source-level buffering (VGPR 52/84 both <<
// resident-buffer need). This version raises TLP instead of fighting the
// scheduler: L=64, H=96, 64 chunks -> 2048 blocks x 128 thr = 4096 waves =
// 16 waves/CU. Even at the measured ~1-2 KB in flight per wave that is
// 16-32 KB/CU -> 10-20 TB/s demand >> 6.3 TB/s ceiling -> HBM-bound with
// 1.6-3x margin, no scheduler cooperation required. Work amp 2.5x -> VALU
// ~17%, far from a ceiling. Halo re-reads are L3-absorbed (measured FETCH
// 188 MiB < compulsory input).

#define DEMA_ALPHA 0.3f
#define DEMA_BETA  0.1f
#define DEMA_T     4096
#define DEMA_B     32
#define DEMA_F     512
#define DEMA_F4    (DEMA_F / 4)      // 128 float4 per (b,t) row
#define DEMA_L     64                // output chunk length
#define DEMA_H     96                // warmup halo length
#define DEMA_C     (DEMA_T / DEMA_L) // 64 chunks

__device__ __forceinline__ void dema_step(float4& s, float4& bb, const float4 xt) {
    const float a  = DEMA_ALPHA;
    const float a1 = 1.0f - DEMA_ALPHA;  // 0.7
    const float be = DEMA_BETA;
    const float b1 = 1.0f - DEMA_BETA;   // 0.9
    float4 sp = s;
    s.x = a * xt.x + a1 * (sp.x + bb.x);
    s.y = a * xt.y + a1 * (sp.y + bb.y);
    s.z = a * xt.z + a1 * (sp.z + bb.z);
    s.w = a * xt.w + a1 * (sp.w + bb.w);
    bb.x = be * (s.x - sp.x) + b1 * bb.x;
    bb.y = be * (s.y - sp.y) + b1 * bb.y;
    bb.z = be * (s.z - sp.z) + b1 * bb.z;
    bb.w = be * (s.w - sp.w) + b1 * bb.w;
}

__global__ __launch_bounds__(128, 4) void dema_kernel(const float* __restrict__ x,
                                                      float* __restrict__ out) {
    const int f4 = threadIdx.x;        // 0..127, coalesced float4 across f
    const int b  = blockIdx.x;         // 0..31
    const int c  = blockIdx.y;         // 0..63 chunk idx

    const float4* __restrict__ xp =
        reinterpret_cast<const float4*>(x) + (size_t)b * DEMA_T * DEMA_F4 + f4;
    float4* __restrict__ op =
        reinterpret_cast<float4*>(out) + (size_t)b * DEMA_T * DEMA_F4 + f4;

    const int t0 = c * DEMA_L;         // chunk start
    float4 s, bb;
    int t;

    if (t0 <= DEMA_H) {
        // Near the sequence start: run the EXACT recurrence from t=0
        // (cheaper than a truncated halo and zero approximation error).
        s = xp[0];
        float4 x1 = xp[DEMA_F4];
        bb.x = x1.x - s.x;             // b_0 = x_1 - x_0
        bb.y = x1.y - s.y;
        bb.z = x1.z - s.z;
        bb.w = x1.w - s.w;
        if (c == 0) op[0] = s;         // out_0 = s_0
        t = 1;
    } else {
        // Approximate state at tw-1: s = x_{tw-1}, b = x_{tw} - x_{tw-1};
        // 96 warmup steps shrink the init error by ||A^96|| ~ 3.6e-8.
        const int tw = t0 - DEMA_H;    // >= 32
        s = xp[(tw - 1) * DEMA_F4];
        float4 x1 = xp[tw * DEMA_F4];
        bb.x = x1.x - s.x;
        bb.y = x1.y - s.y;
        bb.z = x1.z - s.z;
        bb.w = x1.w - s.w;
        t = tw;
    }

    // Warmup: t..t0-1, no stores (63 or 96 iterations; 0 for c==0).
    #pragma unroll 4
    for (; t < t0; ++t) {
        dema_step(s, bb, xp[t * DEMA_F4]);
    }
    // Output: t0..t0+L-1 (for c==0, t starts at 1; op[0] already stored).
    const int tend = t0 + DEMA_L;
    #pragma unroll 4
    for (; t < tend; ++t) {
        dema_step(s, bb, xp[t * DEMA_F4]);
        op[t * DEMA_F4] = s;
    }
}

extern "C" void kernel_launch(void* const* d_in, const int* in_sizes, int n_in,
                              void* d_out, int out_size, void* d_ws, size_t ws_size,
                              hipStream_t stream) {
    const float* x = (const float*)d_in[0];
    float* out = (float*)d_out;

    dim3 block(128, 1, 1);
    dim3 grid(DEMA_B, DEMA_C, 1);      // 32 x 64 = 2048 blocks, 4096 waves
    dema_kernel<<<grid, block, 0, stream>>>(x, out);
}

// Round 17
// 477.281 us; speedup vs baseline: 1.0683x; 1.0683x over previous
//
#include <hip/hip_runtime.h>

// DEMA over x:(B=32, T=4096, F=512) fp32, scan along T.
// Chunked-with-halo: ||A^128|| ~ 1e-9 -> 128-step warmup from cheap init
// (s=x[t-1], b=x[t]-x[t-1]) reproduces state to ~1e-8. L=256,H=128,C=16.
//
// Round-8 post-mortem: 4x occupancy gave only 1.22x BW (2.94 TB/s) ->
// per-wave pipeline depth is the binding constraint and the compiler
// structurally refuses to provide it (sinks tracked loads, drains vmcnt at
// each use; VGPR=20/52/84 across three attempts). This version takes the
// loads away from the compiler: volatile inline-asm global_load_dwordx4
// into a statically-indexed 16-deep VGPR ring + hand-counted
// s_waitcnt vmcnt(N) + sched_barrier(0) after each wait (guide rule #18).
// vmcnt counting includes interleaved stores (single in-order vmcnt stream
// on gfx9). Guarantee rule: a load is complete after s_waitcnt vmcnt(N)
// iff >= N younger VMEM ops were issued after it. Audited per group:
//   c==0: group0 >=15 (W15), groups1..13 =30 (W30), group14 =30 (W30),
//         tail 29-j>=15 (W15).
//   c!=0: warmup =15 (W15), out-group0 15+j>=15 (W15), groups1..14 =30
//         (W30), LAST group 30-j -> W15 (W30 would race for j>=1).
// 16 KB/wave in flight, 64 KB/CU at 4 waves/CU >> Little's-law need.
// Hang-safety: s_waitcnt with N >= outstanding is a no-op; no
// data-dependent loop bounds; no barriers/atomics -> cannot hang.

#define DEMA_ALPHA 0.3f
#define DEMA_BETA  0.1f
#define DEMA_T     4096
#define DEMA_B     32
#define DEMA_F4    128               // float4 per (b,t) row
#define DEMA_L     256               // output chunk length
#define DEMA_H     128               // warmup halo length
#define DEMA_C     (DEMA_T / DEMA_L) // 16 chunks
#define SD         16                // pipeline depth (loads in flight)

typedef float v4f __attribute__((ext_vector_type(4)));

#define SB() __builtin_amdgcn_sched_barrier(0)
#define WAIT15() asm volatile("s_waitcnt vmcnt(15)")
#define WAIT30() asm volatile("s_waitcnt vmcnt(30)")
// "memory" clobber pins the relative order of plain stores vs these loads,
// keeping the vmcnt arithmetic exact (stores cannot migrate across issues).
#define ASM_LOAD(dst, ptr) \
    asm volatile("global_load_dwordx4 %0, %1, off" : "=v"(dst) : "v"(ptr) : "memory")

__device__ __forceinline__ void dema_step(v4f& s, v4f& bb, const v4f xt) {
    const v4f sp = s;
    s  = DEMA_ALPHA * xt + (1.0f - DEMA_ALPHA) * (sp + bb);
    bb = DEMA_BETA * (s - sp) + (1.0f - DEMA_BETA) * bb;
}

__global__ __launch_bounds__(128, 1) void dema_kernel(const float* __restrict__ x,
                                                      float* __restrict__ out) {
    const int f4 = threadIdx.x;        // 0..127, coalesced 16B lanes across F
    const int b  = blockIdx.x;         // 0..31
    const int c  = blockIdx.y;         // 0..15

    const v4f* __restrict__ xp =
        reinterpret_cast<const v4f*>(x) + (size_t)b * DEMA_T * DEMA_F4 + f4;
    v4f* __restrict__ op =
        reinterpret_cast<v4f*>(out) + (size_t)b * DEMA_T * DEMA_F4 + f4;

    v4f buf[SD];                       // VGPR ring, all indices static
    v4f s, bb;

    if (c == 0) {
        // Exact prefix: steps r=1..255 consume xp[r]; ring slot (r-1)%16.
        v4f x0 = xp[0];
        v4f x1 = xp[DEMA_F4];
        s = x0; bb = x1 - x0;
        op[0] = s;                                   // oldest VMEM op, retires first
        #pragma unroll
        for (int j = 0; j < SD; ++j)                 // prologue: loads r=1..16
            ASM_LOAD(buf[j], xp + (size_t)(1 + j) * DEMA_F4);
        // group 0: r=1..16. #younger(load r) >= 15 -> WAIT15 safe.
        #pragma unroll
        for (int j = 0; j < SD; ++j) {
            WAIT15(); SB();
            dema_step(s, bb, buf[j]);
            op[(size_t)(1 + j) * DEMA_F4] = s;
            ASM_LOAD(buf[j], xp + (size_t)(17 + j) * DEMA_F4);
        }
        // groups 1..13: r=17..224, steady: #younger = 30 exactly.
        #pragma unroll 1
        for (int g = 1; g < 14; ++g) {
            #pragma unroll
            for (int j = 0; j < SD; ++j) {
                const int r = 1 + 16 * g + j;
                WAIT30(); SB();
                dema_step(s, bb, buf[j]);
                op[(size_t)r * DEMA_F4] = s;
                ASM_LOAD(buf[j], xp + (size_t)(r + 16) * DEMA_F4);
            }
        }
        // group 14: r=225..240; issues loads 241..255 (j=15 skips).
        #pragma unroll
        for (int j = 0; j < SD; ++j) {
            const int r = 225 + j;
            WAIT30(); SB();
            dema_step(s, bb, buf[j]);
            op[(size_t)r * DEMA_F4] = s;
            if (j < 15) ASM_LOAD(buf[j], xp + (size_t)(r + 16) * DEMA_F4);
        }
        // tail: r=241..255, slots 0..14. #younger = 29-j >= 15 -> WAIT15.
        #pragma unroll
        for (int j = 0; j < 15; ++j) {
            const int r = 241 + j;
            WAIT15(); SB();
            dema_step(s, bb, buf[j]);
            op[(size_t)r * DEMA_F4] = s;
        }
    } else {
        const int t0 = c * DEMA_L;     // >= 256
        const int tw = t0 - DEMA_H;    // >= 128
        const v4f* __restrict__ xw = xp + (size_t)tw * DEMA_F4;
        v4f* __restrict__ ow = op + (size_t)tw * DEMA_F4;

        v4f sm1 = xw[-DEMA_F4];        // x_{tw-1}
        v4f x0  = xw[0];               // x_tw
        s = sm1; bb = x0 - sm1;
        #pragma unroll
        for (int j = 0; j < SD; ++j)                 // prologue: loads r=0..15
            ASM_LOAD(buf[j], xw + (size_t)j * DEMA_F4);
        // Warmup: r=0..127, 8 groups, no stores. #younger = 15 exactly.
        #pragma unroll 1
        for (int g = 0; g < 8; ++g) {
            #pragma unroll
            for (int j = 0; j < SD; ++j) {
                WAIT15(); SB();
                dema_step(s, bb, buf[j]);
                ASM_LOAD(buf[j], xw + (size_t)(16 * g + j + 16) * DEMA_F4);
            }
        }
        // Output group 0: r=128..143. #younger = 15+j >= 15 -> WAIT15.
        #pragma unroll
        for (int j = 0; j < SD; ++j) {
            WAIT15(); SB();
            dema_step(s, bb, buf[j]);
            ow[(size_t)(128 + j) * DEMA_F4] = s;
            ASM_LOAD(buf[j], xw + (size_t)(144 + j) * DEMA_F4);
        }
        // Output groups 1..14: r=144..367, steady #younger = 30.
        #pragma unroll 1
        for (int g = 1; g < 15; ++g) {
            #pragma unroll
            for (int j = 0; j < SD; ++j) {
                const int r = 128 + 16 * g + j;
                WAIT30(); SB();
                dema_step(s, bb, buf[j]);
                ow[(size_t)r * DEMA_F4] = s;
                ASM_LOAD(buf[j], xw + (size_t)(r + 16) * DEMA_F4);  // max 383
            }
        }
        // Last group: r=368..383, no further issues. #younger(L(368+j)) =
        // (15-j) loads + 15 stores = 30-j < 30 for j>=1 -> WAIT30 would be
        // a RACE. 30-j >= 15 for all j -> WAIT15 is the correct guarantee.
        #pragma unroll
        for (int j = 0; j < SD; ++j) {
            WAIT15(); SB();
            dema_step(s, bb, buf[j]);
            ow[(size_t)(368 + j) * DEMA_F4] = s;
        }
    }
}

extern "C" void kernel_launch(void* const* d_in, const int* in_sizes, int n_in,
                              void* d_out, int out_size, void* d_ws, size_t ws_size,
                              hipStream_t stream) {
    const float* x = (const float*)d_in[0];
    float* out = (float*)d_out;

    dim3 block(128, 1, 1);
    dim3 grid(DEMA_B, DEMA_C, 1);      // 32 x 16 = 512 blocks, 1024 waves
    dema_kernel<<<grid, block, 0, stream>>>(x, out);
}

// Round 19
// 475.483 us; speedup vs baseline: 1.0723x; 1.0038x over previous
//
#include <hip/hip_runtime.h>

// DEMA over x:(B=32, T=4096, F=512) fp32, scan along T.
// Chunked-with-halo: ||A^128|| ~ 1e-9 -> 128-step warmup from cheap init
// (s=x[t-1], b=x[t]-x[t-1]) reproduces state to ~1e-8. L=256,H=128,C=16.
//
// Round-17 post-mortem: the asm-ring pipeline survived SCHEDULING but lost
// REGISTER ALLOCATION: VGPR_Count=60 < 64 needed for the 16-deep ring ->
// occupancy-driven spilling moved the ring to scratch, and each spill store
// needs its load retired first -> pipeline re-serialized -> same 2.5 TB/s.
// __launch_bounds__(128,1) only sets MIN waves/EU (VGPR budget); the RA
// still spills chasing 8-wave occupancy this grid can never use (exactly
// 1 wave/EU at 512 blocks). Fix: amdgpu_waves_per_eu(1,1) pins MAX=1 ->
// nothing to gain by spilling -> ring stays in VGPRs. One-attribute change
// vs the audited round-9 artifact; vmcnt ledger untouched.
//
// vmcnt ledger (loads and output stores share one in-order vmcnt stream;
// a load is complete after s_waitcnt vmcnt(N) iff >= N younger VMEM ops
// were issued after it). Audited per group:
//   c==0: group0 >=15 (W15), groups1..13 =30 (W30), group14 =30 (W30),
//         tail 29-j>=15 (W15).
//   c!=0: warmup =15 (W15), out-group0 15+j>=15 (W15), groups1..14 =30
//         (W30), LAST group 30-j -> W15 (W30 would race for j>=1).
// 16 KB/wave in flight, 64 KB/CU at 4 waves/CU >> Little's-law need.
// Hang-safety: over-counted s_waitcnt is a no-op; no data-dependent
// bounds; no barriers/atomics.

#define DEMA_ALPHA 0.3f
#define DEMA_BETA  0.1f
#define DEMA_T     4096
#define DEMA_B     32
#define DEMA_F4    128               // float4 per (b,t) row
#define DEMA_L     256               // output chunk length
#define DEMA_H     128               // warmup halo length
#define DEMA_C     (DEMA_T / DEMA_L) // 16 chunks
#define SD         16                // pipeline depth (loads in flight)

typedef float v4f __attribute__((ext_vector_type(4)));

#define SB() __builtin_amdgcn_sched_barrier(0)
#define WAIT15() asm volatile("s_waitcnt vmcnt(15)")
#define WAIT30() asm volatile("s_waitcnt vmcnt(30)")
// "memory" clobber pins the relative order of plain stores vs these loads,
// keeping the vmcnt arithmetic exact (stores cannot migrate across issues).
#define ASM_LOAD(dst, ptr) \
    asm volatile("global_load_dwordx4 %0, %1, off" : "=v"(dst) : "v"(ptr) : "memory")

__device__ __forceinline__ void dema_step(v4f& s, v4f& bb, const v4f xt) {
    const v4f sp = s;
    s  = DEMA_ALPHA * xt + (1.0f - DEMA_ALPHA) * (sp + bb);
    bb = DEMA_BETA * (s - sp) + (1.0f - DEMA_BETA) * bb;
}

__global__ __launch_bounds__(128)
__attribute__((amdgpu_waves_per_eu(1, 1)))   // pin occupancy target: no
void dema_kernel(const float* __restrict__ x, // occupancy-driven spilling
                 float* __restrict__ out) {
    const int f4 = threadIdx.x;        // 0..127, coalesced 16B lanes across F
    const int b  = blockIdx.x;         // 0..31
    const int c  = blockIdx.y;         // 0..15

    const v4f* __restrict__ xp =
        reinterpret_cast<const v4f*>(x) + (size_t)b * DEMA_T * DEMA_F4 + f4;
    v4f* __restrict__ op =
        reinterpret_cast<v4f*>(out) + (size_t)b * DEMA_T * DEMA_F4 + f4;

    v4f buf[SD];                       // VGPR ring, all indices static
    v4f s, bb;

    if (c == 0) {
        // Exact prefix: steps r=1..255 consume xp[r]; ring slot (r-1)%16.
        v4f x0 = xp[0];
        v4f x1 = xp[DEMA_F4];
        s = x0; bb = x1 - x0;
        op[0] = s;                                   // oldest VMEM op, retires first
        #pragma unroll
        for (int j = 0; j < SD; ++j)                 // prologue: loads r=1..16
            ASM_LOAD(buf[j], xp + (size_t)(1 + j) * DEMA_F4);
        // group 0: r=1..16. #younger(load r) >= 15 -> WAIT15 safe.
        #pragma unroll
        for (int j = 0; j < SD; ++j) {
            WAIT15(); SB();
            dema_step(s, bb, buf[j]);
            op[(size_t)(1 + j) * DEMA_F4] = s;
            ASM_LOAD(buf[j], xp + (size_t)(17 + j) * DEMA_F4);
        }
        // groups 1..13: r=17..224, steady: #younger = 30 exactly.
        #pragma unroll 1
        for (int g = 1; g < 14; ++g) {
            #pragma unroll
            for (int j = 0; j < SD; ++j) {
                const int r = 1 + 16 * g + j;
                WAIT30(); SB();
                dema_step(s, bb, buf[j]);
                op[(size_t)r * DEMA_F4] = s;
                ASM_LOAD(buf[j], xp + (size_t)(r + 16) * DEMA_F4);
            }
        }
        // group 14: r=225..240; issues loads 241..255 (j=15 skips).
        #pragma unroll
        for (int j = 0; j < SD; ++j) {
            const int r = 225 + j;
            WAIT30(); SB();
            dema_step(s, bb, buf[j]);
            op[(size_t)r * DEMA_F4] = s;
            if (j < 15) ASM_LOAD(buf[j], xp + (size_t)(r + 16) * DEMA_F4);
        }
        // tail: r=241..255, slots 0..14. #younger = 29-j >= 15 -> WAIT15.
        #pragma unroll
        for (int j = 0; j < 15; ++j) {
            const int r = 241 + j;
            WAIT15(); SB();
            dema_step(s, bb, buf[j]);
            op[(size_t)r * DEMA_F4] = s;
        }
    } else {
        const int t0 = c * DEMA_L;     // >= 256
        const int tw = t0 - DEMA_H;    // >= 128
        const v4f* __restrict__ xw = xp + (size_t)tw * DEMA_F4;
        v4f* __restrict__ ow = op + (size_t)tw * DEMA_F4;

        v4f sm1 = xw[-DEMA_F4];        // x_{tw-1}
        v4f x0  = xw[0];               // x_tw
        s = sm1; bb = x0 - sm1;
        #pragma unroll
        for (int j = 0; j < SD; ++j)                 // prologue: loads r=0..15
            ASM_LOAD(buf[j], xw + (size_t)j * DEMA_F4);
        // Warmup: r=0..127, 8 groups, no stores. #younger = 15 exactly.
        #pragma unroll 1
        for (int g = 0; g < 8; ++g) {
            #pragma unroll
            for (int j = 0; j < SD; ++j) {
                WAIT15(); SB();
                dema_step(s, bb, buf[j]);
                ASM_LOAD(buf[j], xw + (size_t)(16 * g + j + 16) * DEMA_F4);
            }
        }
        // Output group 0: r=128..143. #younger = 15+j >= 15 -> WAIT15.
        #pragma unroll
        for (int j = 0; j < SD; ++j) {
            WAIT15(); SB();
            dema_step(s, bb, buf[j]);
            ow[(size_t)(128 + j) * DEMA_F4] = s;
            ASM_LOAD(buf[j], xw + (size_t)(144 + j) * DEMA_F4);
        }
        // Output groups 1..14: r=144..367, steady #younger = 30.
        #pragma unroll 1
        for (int g = 1; g < 15; ++g) {
            #pragma unroll
            for (int j = 0; j < SD; ++j) {
                const int r = 128 + 16 * g + j;
                WAIT30(); SB();
                dema_step(s, bb, buf[j]);
                ow[(size_t)r * DEMA_F4] = s;
                ASM_LOAD(buf[j], xw + (size_t)(r + 16) * DEMA_F4);  // max 383
            }
        }
        // Last group: r=368..383, no further issues. #younger(L(368+j)) =
        // (15-j) loads + 15 stores = 30-j < 30 for j>=1 -> WAIT30 would be
        // a RACE. 30-j >= 15 for all j -> WAIT15 is the correct guarantee.
        #pragma unroll
        for (int j = 0; j < SD; ++j) {
            WAIT15(); SB();
            dema_step(s, bb, buf[j]);
            ow[(size_t)(368 + j) * DEMA_F4] = s;
        }
    }
}

extern "C" void kernel_launch(void* const* d_in, const int* in_sizes, int n_in,
                              void* d_out, int out_size, void* d_ws, size_t ws_size,
                              hipStream_t stream) {
    const float* x = (const float*)d_in[0];
    float* out = (float*)d_out;

    dim3 block(128, 1, 1);
    dim3 grid(DEMA_B, DEMA_C, 1);      // 32 x 16 = 512 blocks, 1024 waves
    dema_kernel<<<grid, block, 0, stream>>>(x, out);
}